// Round 1
// baseline (566.674 us; speedup 1.0000x reference)
//
#include <hip/hip_runtime.h>

#define V 50000
#define E_DIM 256
#define H_DIM 512
#define H2 1024
#define G3 1536
#define BSZ 64
#define SEQ 200
#define KX 1280
#define MROWS 12800

// ws layout (floats)
#define X_OFF   0        // 64*1280
#define H0_OFF  81920    // 64*512
#define GI_OFF  114688   // 64*1536
#define GH_OFF  212992   // 64*1536
#define SC_OFF  311296   // 12800
#define RED4_OFF 324096  // 64*4*2
#define RED_OFF  324608  // 64*2

// d_out layout (floats)
#define OUT_STATE 3200000
#define OUT_W     3232768

__device__ __forceinline__ float sigmf(float x) { return 1.f / (1.f + __expf(-x)); }

// ---------------- K0: build x = [embed | weighted], h0 = effective prev_state
__global__ void k0_build(const int* __restrict__ input_idx, const float* __restrict__ encoded,
                         const float* __restrict__ prev_state, const float* __restrict__ weighted,
                         const int* __restrict__ order_p, const float* __restrict__ embed_W,
                         const float* __restrict__ Ws_W, const float* __restrict__ Ws_b,
                         float* __restrict__ ws) {
  float* x = ws + X_OFF;
  float* h0 = ws + H0_OFF;
  int b = blockIdx.x, tid = threadIdx.x;
  int order = order_p[0];
  int idx = input_idx[b];
  x[b * KX + tid] = embed_W[(size_t)idx * E_DIM + tid];
  if (order != 0) {
    for (int j = tid; j < H2; j += 256) x[b * KX + E_DIM + j] = weighted[b * H2 + j];
    for (int j = tid; j < H_DIM; j += 256) h0[b * H_DIM + j] = prev_state[b * H_DIM + j];
  } else {
    for (int j = tid; j < H2; j += 256) x[b * KX + E_DIM + j] = 0.f;
    const float* er = encoded + ((size_t)b * SEQ + 1) * H2;
    for (int j = tid; j < H_DIM; j += 256) {
      float acc = Ws_b[j];
      const float* wr = Ws_W + (size_t)j * H2;
      for (int k = 0; k < H2; ++k) acc = fmaf(er[k], wr[k], acc);
      h0[b * H_DIM + j] = acc;
    }
  }
}

// ---------------- generic: out[b][n] = A[b][:] . W[n][:] + bias[n]
// lane = n (coalesced stores), W staged in LDS (pad 68 => P%32==4 -> conflict-free b128),
// A rows read as wave-uniform float4 (L1 broadcast).
template <int KDIM, int BPW>
__global__ __launch_bounds__(256) void gemm_nT(const float* __restrict__ A,
                                               const float* __restrict__ W,
                                               const float* __restrict__ bias,
                                               float* __restrict__ out, int N) {
  __shared__ float Ws_[64][68];
  int tid = threadIdx.x;
  int lane = tid & 63, wv = tid >> 6;
  int n0 = blockIdx.x * 64;
  int b0 = blockIdx.y * (4 * BPW) + wv * BPW;
  float acc[BPW];
#pragma unroll
  for (int i = 0; i < BPW; ++i) acc[i] = 0.f;
  for (int k0 = 0; k0 < KDIM; k0 += 64) {
    __syncthreads();
#pragma unroll
    for (int i = 0; i < 4; ++i) {
      int row = i * 16 + (tid >> 4);
      int c4 = (tid & 15) * 4;
      int rr = n0 + row;
      rr = rr < N ? rr : N - 1;
      *(float4*)&Ws_[row][c4] = *(const float4*)&W[(size_t)rr * KDIM + k0 + c4];
    }
    __syncthreads();
#pragma unroll 2
    for (int k = 0; k < 64; k += 4) {
      float4 wvv = *(const float4*)&Ws_[lane][k];
#pragma unroll
      for (int i = 0; i < BPW; ++i) {
        float4 av = *(const float4*)&A[(size_t)(b0 + i) * KDIM + k0 + k];
        acc[i] = fmaf(wvv.x, av.x, acc[i]);
        acc[i] = fmaf(wvv.y, av.y, acc[i]);
        acc[i] = fmaf(wvv.z, av.z, acc[i]);
        acc[i] = fmaf(wvv.w, av.w, acc[i]);
      }
    }
  }
  int n = n0 + lane;
  if (n < N) {
    float bv = bias[n];
#pragma unroll
    for (int i = 0; i < BPW; ++i) out[(size_t)(b0 + i) * N + n] = acc[i] + bv;
  }
}

// ---------------- K2: GRU cell elementwise -> state (written to d_out state slot)
__global__ void k2_gru(const float* __restrict__ gi, const float* __restrict__ gh,
                       const float* __restrict__ h0, float* __restrict__ state_out) {
  int b = blockIdx.x, j = threadIdx.x;  // block = 512
  float ir = gi[b * G3 + j], iz = gi[b * G3 + H_DIM + j], inn = gi[b * G3 + 2 * H_DIM + j];
  float hr = gh[b * G3 + j], hz = gh[b * G3 + H_DIM + j], hn = gh[b * G3 + 2 * H_DIM + j];
  float r = sigmf(ir + hr);
  float z = sigmf(iz + hz);
  float n = tanhf(inn + r * hn);
  state_out[b * H_DIM + j] = (1.f - z) * n + z * h0[b * H_DIM + j];
}

// ---------------- K4: score_c partials: sum_h tanh(enc@WcT + b) * state
// classic 128x128 tile, 8x8 per thread, f32.
__global__ __launch_bounds__(256) void k4_scorec(const float* __restrict__ encoded,
                                                 const float* __restrict__ Wc_W,
                                                 const float* __restrict__ Wc_b,
                                                 const float* __restrict__ state,
                                                 float* __restrict__ score_c) {
  __shared__ float es[32][132];
  __shared__ float wcs[32][132];
  __shared__ float reds[16][129];
  int tid = threadIdx.x;
  int bm = blockIdx.x, bn = blockIdx.y;
  int m0 = (tid & 15) * 8, n0 = (tid >> 4) * 8;
  int r0 = bm * 128, c0 = bn * 128;
  float acc[8][8];
#pragma unroll
  for (int i = 0; i < 8; ++i)
#pragma unroll
    for (int j = 0; j < 8; ++j) acc[i][j] = 0.f;

  for (int k0 = 0; k0 < H2; k0 += 32) {
    __syncthreads();
#pragma unroll
    for (int i = 0; i < 4; ++i) {
      int e = tid + i * 256;
      int ml = e >> 3, k4 = (e & 7) * 4;
      float4 v = *(const float4*)&encoded[(size_t)(r0 + ml) * H2 + k0 + k4];
      es[k4][ml] = v.x; es[k4 + 1][ml] = v.y; es[k4 + 2][ml] = v.z; es[k4 + 3][ml] = v.w;
      float4 u = *(const float4*)&Wc_W[(size_t)(c0 + ml) * H2 + k0 + k4];
      wcs[k4][ml] = u.x; wcs[k4 + 1][ml] = u.y; wcs[k4 + 2][ml] = u.z; wcs[k4 + 3][ml] = u.w;
    }
    __syncthreads();
#pragma unroll 4
    for (int k = 0; k < 32; ++k) {
      float4 a0 = *(const float4*)&es[k][m0];
      float4 a1 = *(const float4*)&es[k][m0 + 4];
      float4 b0v = *(const float4*)&wcs[k][n0];
      float4 b1v = *(const float4*)&wcs[k][n0 + 4];
      float am[8] = {a0.x, a0.y, a0.z, a0.w, a1.x, a1.y, a1.z, a1.w};
      float bv[8] = {b0v.x, b0v.y, b0v.z, b0v.w, b1v.x, b1v.y, b1v.z, b1v.w};
#pragma unroll
      for (int i = 0; i < 8; ++i)
#pragma unroll
        for (int j = 0; j < 8; ++j) acc[i][j] = fmaf(am[i], bv[j], acc[i][j]);
    }
  }
  // epilogue: tanh(+bias) * state, reduce over local n
  float bias[8];
#pragma unroll
  for (int j = 0; j < 8; ++j) bias[j] = Wc_b[c0 + n0 + j];
  float part[8];
#pragma unroll
  for (int i = 0; i < 8; ++i) {
    int gm = r0 + m0 + i;
    int b = gm / 200;
    const float* st = state + b * H_DIM + c0 + n0;
    float p = 0.f;
#pragma unroll
    for (int j = 0; j < 8; ++j) p += tanhf(acc[i][j] + bias[j]) * st[j];
    part[i] = p;
  }
  __syncthreads();
#pragma unroll
  for (int i = 0; i < 8; ++i) reds[tid >> 4][m0 + i] = part[i];
  __syncthreads();
  if (tid < 128) {
    float s = 0.f;
#pragma unroll
    for (int g = 0; g < 16; ++g) s += reds[g][tid];
    atomicAdd(&score_c[r0 + tid], s);
  }
}

// ---------------- K6: online (max, sumexp) partials over [score_g | score_c]
__global__ void k6_red(const float* __restrict__ sg, const float* __restrict__ scraw,
                       const int* __restrict__ eidx, float* __restrict__ red4) {
  int b = blockIdx.x, c = blockIdx.y, tid = threadIdx.x;
  float m = -1e30f, s = 0.f;
  const float4* row = (const float4*)(sg + (size_t)b * V);
  int start = c * 3125, end = start + 3125;
  for (int i = start + tid; i < end; i += 256) {
    float4 v = row[i];
    float vv[4] = {v.x, v.y, v.z, v.w};
#pragma unroll
    for (int q = 0; q < 4; ++q) {
      float xx = vv[q];
      if (xx > m) { s *= __expf(m - xx); m = xx; }
      s += __expf(xx - m);
    }
  }
  if (c == 3) {
    for (int i = tid; i < SEQ; i += 256) {
      float sc = tanhf(scraw[b * SEQ + i] + (eidx[b * SEQ + i] == 0 ? -1000.f : 0.f));
      if (sc > m) { s *= __expf(m - sc); m = sc; }
      s += __expf(sc - m);
    }
  }
  __shared__ float ms[256], ssh[256];
  ms[tid] = m; ssh[tid] = s;
  __syncthreads();
  for (int off = 128; off > 0; off >>= 1) {
    if (tid < off) {
      float m2 = ms[tid + off], s2 = ssh[tid + off];
      float mn = fmaxf(ms[tid], m2);
      ssh[tid] = ssh[tid] * __expf(ms[tid] - mn) + s2 * __expf(m2 - mn);
      ms[tid] = mn;
    }
    __syncthreads();
  }
  if (tid == 0) {
    red4[(b * 4 + c) * 2] = ms[0];
    red4[(b * 4 + c) * 2 + 1] = ssh[0];
  }
}

__global__ void k6b_combine(const float* __restrict__ red4, float* __restrict__ red) {
  int b = threadIdx.x;  // 64
  float m = -1e30f, s = 0.f;
  for (int c = 0; c < 4; ++c) {
    float m2 = red4[(b * 4 + c) * 2], s2 = red4[(b * 4 + c) * 2 + 1];
    float mn = fmaxf(m, m2);
    s = s * __expf(m - mn) + s2 * __expf(m2 - mn);
    m = mn;
  }
  red[b * 2] = m;
  red[b * 2 + 1] = s;
}

// ---------------- K7: score_g -> prob_g in place
__global__ void k7_probs(float* __restrict__ sg, const float* __restrict__ red) {
  int i = blockIdx.x * 256 + threadIdx.x;  // 0..799999 float4s
  int b = i / 12500;
  float mm = red[b * 2], rd = 1.f / red[b * 2 + 1];
  float4* p = (float4*)sg;
  float4 v = p[i];
  v.x = __expf(v.x - mm) * rd;
  v.y = __expf(v.y - mm) * rd;
  v.z = __expf(v.z - mm) * rd;
  v.w = __expf(v.w - mm) * rd;
  p[i] = v;
}

// ---------------- K8: prob_c scatter-add into out + match-attn weighted sum
__global__ void k8_copy(const float* __restrict__ score_c, const int* __restrict__ eidx,
                        const int* __restrict__ input_idx, const float* __restrict__ red,
                        const float* __restrict__ encoded, float* __restrict__ out,
                        float* __restrict__ wout) {
  int b = blockIdx.x, tid = threadIdx.x;
  __shared__ float att_s[SEQ];
  __shared__ int cnt_s[256];
  float mm = red[b * 2], rd = 1.f / red[b * 2 + 1];
  int inp = input_idx[b];
  int cnt = 0;
  for (int s = tid; s < SEQ; s += 256) {
    int ei = eidx[b * SEQ + s];
    float sc = tanhf(score_c[b * SEQ + s] + (ei == 0 ? -1000.f : 0.f));
    float p = __expf(sc - mm) * rd;
    bool mt = (ei == inp);
    att_s[s] = mt ? p : 0.f;
    cnt += mt ? 1 : 0;
    atomicAdd(&out[(size_t)b * V + ei], p);
  }
  cnt_s[tid] = cnt;
  __syncthreads();
  for (int off = 128; off > 0; off >>= 1) {
    if (tid < off) cnt_s[tid] += cnt_s[tid + off];
    __syncthreads();
  }
  int c = cnt_s[0];
  float scale = (c > 1) ? 1.f / (float)c : 1.f;
  float w0 = 0, w1 = 0, w2 = 0, w3 = 0;
  for (int s = 0; s < SEQ; ++s) {
    float a = att_s[s];
    if (a != 0.f) {
      const float* er = encoded + ((size_t)b * SEQ + s) * H2;
      w0 += a * er[tid];
      w1 += a * er[tid + 256];
      w2 += a * er[tid + 512];
      w3 += a * er[tid + 768];
    }
  }
  wout[b * H2 + tid] = w0 * scale;
  wout[b * H2 + tid + 256] = w1 * scale;
  wout[b * H2 + tid + 512] = w2 * scale;
  wout[b * H2 + tid + 768] = w3 * scale;
}

extern "C" void kernel_launch(void* const* d_in, const int* in_sizes, int n_in,
                              void* d_out, int out_size, void* d_ws, size_t ws_size,
                              hipStream_t stream) {
  const int* input_idx = (const int*)d_in[0];
  const float* encoded = (const float*)d_in[1];
  const int* encoded_idx = (const int*)d_in[2];
  const float* prev_state = (const float*)d_in[3];
  const float* weighted = (const float*)d_in[4];
  const int* order_p = (const int*)d_in[5];
  const float* embed_W = (const float*)d_in[6];
  const float* Wih = (const float*)d_in[7];
  const float* Whh = (const float*)d_in[8];
  const float* bih = (const float*)d_in[9];
  const float* bhh = (const float*)d_in[10];
  const float* Ws_W = (const float*)d_in[11];
  const float* Ws_b = (const float*)d_in[12];
  const float* Wo_W = (const float*)d_in[13];
  const float* Wo_b = (const float*)d_in[14];
  const float* Wc_W = (const float*)d_in[15];
  const float* Wc_b = (const float*)d_in[16];

  float* ws = (float*)d_ws;
  float* out = (float*)d_out;
  float* x = ws + X_OFF;
  float* h0 = ws + H0_OFF;
  float* gi = ws + GI_OFF;
  float* gh = ws + GH_OFF;
  float* score_c = ws + SC_OFF;
  float* red4 = ws + RED4_OFF;
  float* red = ws + RED_OFF;
  float* state = out + OUT_STATE;
  float* wout = out + OUT_W;

  hipMemsetAsync(score_c, 0, MROWS * sizeof(float), stream);
  k0_build<<<64, 256, 0, stream>>>(input_idx, encoded, prev_state, weighted, order_p,
                                   embed_W, Ws_W, Ws_b, ws);
  gemm_nT<KX, 4><<<dim3(24, 4), 256, 0, stream>>>(x, Wih, bih, gi, G3);
  gemm_nT<H_DIM, 4><<<dim3(24, 4), 256, 0, stream>>>(h0, Whh, bhh, gh, G3);
  k2_gru<<<64, 512, 0, stream>>>(gi, gh, h0, state);
  gemm_nT<H_DIM, 16><<<dim3(782, 1), 256, 0, stream>>>(state, Wo_W, Wo_b, out, V);
  k4_scorec<<<dim3(100, 4), 256, 0, stream>>>(encoded, Wc_W, Wc_b, state, score_c);
  k6_red<<<dim3(64, 4), 256, 0, stream>>>(out, score_c, encoded_idx, red4);
  k6b_combine<<<1, 64, 0, stream>>>(red4, red);
  k7_probs<<<3125, 256, 0, stream>>>(out, red);
  k8_copy<<<64, 256, 0, stream>>>(score_c, encoded_idx, input_idx, red, encoded, out, wout);
}

// Round 2
// 207.499 us; speedup vs baseline: 2.7310x; 2.7310x over previous
//
#include <hip/hip_runtime.h>

#define V 50000
#define E_DIM 256
#define H_DIM 512
#define H2 1024
#define G3 1536
#define BSZ 64
#define SEQ 200
#define KX 1280
#define MROWS 12800

// ws layout (float slots)
#define XBF_OFF   0        // 64*1280 bf16 = 40960 f
#define H0_OFF    40960    // 64*512 f32
#define H0BF_OFF  73728    // 64*512 bf16 = 16384 f
#define GI_OFF    90112    // 64*1536 f32
#define GH_OFF    188416   // 64*1536 f32
#define STBF_OFF  286720   // 64*512 bf16 = 16384 f
#define WCBF_OFF  303104   // 512*1024 bf16 = 262144 f
#define SC_OFF    565248   // 12800 f32
#define RED4_OFF  578048   // 64*4*2
#define RED_OFF   578560   // 64*2

// d_out layout (floats)
#define OUT_STATE 3200000
#define OUT_W     3232768

typedef __attribute__((ext_vector_type(8))) short bf16x8;
typedef __attribute__((ext_vector_type(4))) float f32x4;

__device__ __forceinline__ float sigmf(float x) { return 1.f / (1.f + __expf(-x)); }

__device__ __forceinline__ ushort f2bf(float f) {
  uint u = __float_as_uint(f);
  uint r = (u + 0x7FFFu + ((u >> 16) & 1u)) >> 16;
  return (ushort)r;
}

__device__ __forceinline__ bf16x8 cvt8(float4 a, float4 b) {
  bf16x8 r;
  r[0] = (short)f2bf(a.x); r[1] = (short)f2bf(a.y);
  r[2] = (short)f2bf(a.z); r[3] = (short)f2bf(a.w);
  r[4] = (short)f2bf(b.x); r[5] = (short)f2bf(b.y);
  r[6] = (short)f2bf(b.z); r[7] = (short)f2bf(b.w);
  return r;
}

// ---------------- kcvt: f32 -> bf16 bulk convert (for Wc_W)
__global__ void kcvt(const float* __restrict__ W, ushort* __restrict__ Wbf) {
  int i = blockIdx.x * 256 + threadIdx.x;  // one float4 each
  float4 v = ((const float4*)W)[i];
  ushort4 o;
  o.x = f2bf(v.x); o.y = f2bf(v.y); o.z = f2bf(v.z); o.w = f2bf(v.w);
  ((ushort4*)Wbf)[i] = o;
}

// ---------------- K0: x_bf = [embed | weighted] bf16, h0 (f32 + bf16)
__global__ void k0_build(const int* __restrict__ input_idx, const float* __restrict__ encoded,
                         const float* __restrict__ prev_state, const float* __restrict__ weighted,
                         const int* __restrict__ order_p, const float* __restrict__ embed_W,
                         const float* __restrict__ Ws_W, const float* __restrict__ Ws_b,
                         ushort* __restrict__ x_bf, float* __restrict__ h0,
                         ushort* __restrict__ h0_bf) {
  int b = blockIdx.x, tid = threadIdx.x;
  int order = order_p[0];
  int idx = input_idx[b];
  x_bf[b * KX + tid] = f2bf(embed_W[(size_t)idx * E_DIM + tid]);
  if (order != 0) {
    for (int j = tid; j < H2; j += 256) x_bf[b * KX + E_DIM + j] = f2bf(weighted[b * H2 + j]);
    for (int j = tid; j < H_DIM; j += 256) {
      float v = prev_state[b * H_DIM + j];
      h0[b * H_DIM + j] = v;
      h0_bf[b * H_DIM + j] = f2bf(v);
    }
  } else {
    for (int j = tid; j < H2; j += 256) x_bf[b * KX + E_DIM + j] = 0;
    const float* er = encoded + ((size_t)b * SEQ + 1) * H2;
    for (int j = tid; j < H_DIM; j += 256) {
      float acc = Ws_b[j];
      const float* wr = Ws_W + (size_t)j * H2;
      for (int k = 0; k < H2; ++k) acc = fmaf(er[k], wr[k], acc);
      h0[b * H_DIM + j] = acc;
      h0_bf[b * H_DIM + j] = f2bf(acc);
    }
  }
}

// ---------------- MFMA GEMM: out[m][n] = A[m][:] . W[n][:] + bias[n]
// A: [64][KDIM] bf16. W: [N][KDIM] f32 (converted on the fly). Wave owns 16 n's,
// all 64 m's (4 m-tiles). No LDS; state/A is small & cache-resident.
template <int KDIM>
__global__ __launch_bounds__(256) void mfma_bt(const ushort* __restrict__ Abf,
                                               const float* __restrict__ W,
                                               const float* __restrict__ bias,
                                               float* __restrict__ out, int N) {
  int tid = threadIdx.x;
  int lane = tid & 63, wv = tid >> 6;
  int n0 = (blockIdx.x * 4 + wv) * 16;
  if (n0 >= N) return;
  int l15 = lane & 15, lg = lane >> 4;
  f32x4 acc[4];
#pragma unroll
  for (int mt = 0; mt < 4; ++mt) acc[mt] = (f32x4){0.f, 0.f, 0.f, 0.f};
  const float* wrow = W + (size_t)(n0 + l15) * KDIM + lg * 8;
  const ushort* arow = Abf + (size_t)l15 * KDIM + lg * 8;
#pragma unroll 2
  for (int k0 = 0; k0 < KDIM; k0 += 32) {
    float4 w0 = *(const float4*)(wrow + k0);
    float4 w1 = *(const float4*)(wrow + k0 + 4);
    bf16x8 bf = cvt8(w0, w1);
#pragma unroll
    for (int mt = 0; mt < 4; ++mt) {
      bf16x8 af = *(const bf16x8*)(arow + mt * 16 * KDIM + k0);
      acc[mt] = __builtin_amdgcn_mfma_f32_16x16x32_bf16(af, bf, acc[mt], 0, 0, 0);
    }
  }
  float bv = bias[n0 + l15];
#pragma unroll
  for (int mt = 0; mt < 4; ++mt)
#pragma unroll
    for (int r = 0; r < 4; ++r)
      out[(size_t)(mt * 16 + lg * 4 + r) * N + n0 + l15] = acc[mt][r] + bv;
}

// ---------------- K2: GRU cell -> state f32 (d_out) + state bf16 (ws)
__global__ void k2_gru(const float* __restrict__ gi, const float* __restrict__ gh,
                       const float* __restrict__ h0, float* __restrict__ state_out,
                       ushort* __restrict__ state_bf) {
  int b = blockIdx.x, j = threadIdx.x;  // block = 512
  float ir = gi[b * G3 + j], iz = gi[b * G3 + H_DIM + j], inn = gi[b * G3 + 2 * H_DIM + j];
  float hr = gh[b * G3 + j], hz = gh[b * G3 + H_DIM + j], hn = gh[b * G3 + 2 * H_DIM + j];
  float r = sigmf(ir + hr);
  float z = sigmf(iz + hz);
  float n = tanhf(inn + r * hn);
  float st = (1.f - z) * n + z * h0[b * H_DIM + j];
  state_out[b * H_DIM + j] = st;
  state_bf[b * H_DIM + j] = f2bf(st);
}

// ---------------- K4: score_c[m] = sum_n tanh( (enc @ WcT)[m][n] + b[n] ) * state[b][n]
// MFMA: block = 64 rows, wave = 16 rows x all 512 n (acc[32]); Wc bf16 k-slice in LDS.
__global__ __launch_bounds__(256, 1) void k4_mfma(const float* __restrict__ encoded,
                                                  const ushort* __restrict__ Wc_bf,
                                                  const float* __restrict__ Wc_b,
                                                  const float* __restrict__ state,
                                                  float* __restrict__ score_c) {
  __shared__ ushort Bs[512][40];  // pad 32->40: 2-way bank alias only (free)
  int tid = threadIdx.x, lane = tid & 63, wv = tid >> 6;
  int l15 = lane & 15, lg = lane >> 4;
  int m0w = blockIdx.x * 64 + wv * 16;
  f32x4 acc[32];
#pragma unroll
  for (int nt = 0; nt < 32; ++nt) acc[nt] = (f32x4){0.f, 0.f, 0.f, 0.f};
  const float* arow = encoded + (size_t)(m0w + l15) * H2 + lg * 8;

  for (int k0 = 0; k0 < H2; k0 += 32) {
    __syncthreads();
#pragma unroll
    for (int i = 0; i < 8; ++i) {
      int idx = tid + i * 256;
      int n = idx >> 2, k8 = (idx & 3) * 8;
      *(bf16x8*)&Bs[n][k8] = *(const bf16x8*)(Wc_bf + (size_t)n * H2 + k0 + k8);
    }
    __syncthreads();
    float4 a0 = *(const float4*)(arow + k0);
    float4 a1 = *(const float4*)(arow + k0 + 4);
    bf16x8 af = cvt8(a0, a1);
#pragma unroll
    for (int nt = 0; nt < 32; ++nt) {
      bf16x8 bf = *(const bf16x8*)&Bs[nt * 16 + l15][lg * 8];
      acc[nt] = __builtin_amdgcn_mfma_f32_16x16x32_bf16(af, bf, acc[nt], 0, 0, 0);
    }
  }
  // epilogue: tanh(+bias)*state, reduce over n
  float pv[4] = {0.f, 0.f, 0.f, 0.f};
#pragma unroll
  for (int nt = 0; nt < 32; ++nt) {
    int n = nt * 16 + l15;
    float bias = Wc_b[n];
#pragma unroll
    for (int r = 0; r < 4; ++r) {
      int m = m0w + lg * 4 + r;
      int b = m / SEQ;
      pv[r] += tanhf(acc[nt][r] + bias) * state[b * H_DIM + n];
    }
  }
#pragma unroll
  for (int off = 1; off < 16; off <<= 1)
#pragma unroll
    for (int r = 0; r < 4; ++r) pv[r] += __shfl_xor(pv[r], off, 64);
  if (l15 == 0) {
#pragma unroll
    for (int r = 0; r < 4; ++r) score_c[m0w + lg * 4 + r] = pv[r];
  }
}

// ---------------- K6: online (max, sumexp) partials over [score_g | score_c]
__global__ void k6_red(const float* __restrict__ sg, const float* __restrict__ scraw,
                       const int* __restrict__ eidx, float* __restrict__ red4) {
  int b = blockIdx.x, c = blockIdx.y, tid = threadIdx.x;
  float m = -1e30f, s = 0.f;
  const float4* row = (const float4*)(sg + (size_t)b * V);
  int start = c * 3125, end = start + 3125;
  for (int i = start + tid; i < end; i += 256) {
    float4 v = row[i];
    float vv[4] = {v.x, v.y, v.z, v.w};
#pragma unroll
    for (int q = 0; q < 4; ++q) {
      float xx = vv[q];
      if (xx > m) { s *= __expf(m - xx); m = xx; }
      s += __expf(xx - m);
    }
  }
  if (c == 3) {
    for (int i = tid; i < SEQ; i += 256) {
      float sc = tanhf(scraw[b * SEQ + i] + (eidx[b * SEQ + i] == 0 ? -1000.f : 0.f));
      if (sc > m) { s *= __expf(m - sc); m = sc; }
      s += __expf(sc - m);
    }
  }
  __shared__ float ms[256], ssh[256];
  ms[tid] = m; ssh[tid] = s;
  __syncthreads();
  for (int off = 128; off > 0; off >>= 1) {
    if (tid < off) {
      float m2 = ms[tid + off], s2 = ssh[tid + off];
      float mn = fmaxf(ms[tid], m2);
      ssh[tid] = ssh[tid] * __expf(ms[tid] - mn) + s2 * __expf(m2 - mn);
      ms[tid] = mn;
    }
    __syncthreads();
  }
  if (tid == 0) {
    red4[(b * 4 + c) * 2] = ms[0];
    red4[(b * 4 + c) * 2 + 1] = ssh[0];
  }
}

__global__ void k6b_combine(const float* __restrict__ red4, float* __restrict__ red) {
  int b = threadIdx.x;  // 64
  float m = -1e30f, s = 0.f;
  for (int c = 0; c < 4; ++c) {
    float m2 = red4[(b * 4 + c) * 2], s2 = red4[(b * 4 + c) * 2 + 1];
    float mn = fmaxf(m, m2);
    s = s * __expf(m - mn) + s2 * __expf(m2 - mn);
    m = mn;
  }
  red[b * 2] = m;
  red[b * 2 + 1] = s;
}

// ---------------- K7: score_g -> prob_g in place
__global__ void k7_probs(float* __restrict__ sg, const float* __restrict__ red) {
  int i = blockIdx.x * 256 + threadIdx.x;
  int b = i / 12500;
  float mm = red[b * 2], rd = 1.f / red[b * 2 + 1];
  float4* p = (float4*)sg;
  float4 v = p[i];
  v.x = __expf(v.x - mm) * rd;
  v.y = __expf(v.y - mm) * rd;
  v.z = __expf(v.z - mm) * rd;
  v.w = __expf(v.w - mm) * rd;
  p[i] = v;
}

// ---------------- K8: prob_c scatter-add into out + match-attn weighted sum
__global__ void k8_copy(const float* __restrict__ score_c, const int* __restrict__ eidx,
                        const int* __restrict__ input_idx, const float* __restrict__ red,
                        const float* __restrict__ encoded, float* __restrict__ out,
                        float* __restrict__ wout) {
  int b = blockIdx.x, tid = threadIdx.x;
  __shared__ float att_s[SEQ];
  __shared__ int cnt_s[256];
  float mm = red[b * 2], rd = 1.f / red[b * 2 + 1];
  int inp = input_idx[b];
  int cnt = 0;
  for (int s = tid; s < SEQ; s += 256) {
    int ei = eidx[b * SEQ + s];
    float sc = tanhf(score_c[b * SEQ + s] + (ei == 0 ? -1000.f : 0.f));
    float p = __expf(sc - mm) * rd;
    bool mt = (ei == inp);
    att_s[s] = mt ? p : 0.f;
    cnt += mt ? 1 : 0;
    atomicAdd(&out[(size_t)b * V + ei], p);
  }
  cnt_s[tid] = cnt;
  __syncthreads();
  for (int off = 128; off > 0; off >>= 1) {
    if (tid < off) cnt_s[tid] += cnt_s[tid + off];
    __syncthreads();
  }
  int c = cnt_s[0];
  float scale = (c > 1) ? 1.f / (float)c : 1.f;
  float w0 = 0, w1 = 0, w2 = 0, w3 = 0;
  for (int s = 0; s < SEQ; ++s) {
    float a = att_s[s];
    if (a != 0.f) {
      const float* er = encoded + ((size_t)b * SEQ + s) * H2;
      w0 += a * er[tid];
      w1 += a * er[tid + 256];
      w2 += a * er[tid + 512];
      w3 += a * er[tid + 768];
    }
  }
  wout[b * H2 + tid] = w0 * scale;
  wout[b * H2 + tid + 256] = w1 * scale;
  wout[b * H2 + tid + 512] = w2 * scale;
  wout[b * H2 + tid + 768] = w3 * scale;
}

extern "C" void kernel_launch(void* const* d_in, const int* in_sizes, int n_in,
                              void* d_out, int out_size, void* d_ws, size_t ws_size,
                              hipStream_t stream) {
  const int* input_idx = (const int*)d_in[0];
  const float* encoded = (const float*)d_in[1];
  const int* encoded_idx = (const int*)d_in[2];
  const float* prev_state = (const float*)d_in[3];
  const float* weighted = (const float*)d_in[4];
  const int* order_p = (const int*)d_in[5];
  const float* embed_W = (const float*)d_in[6];
  const float* Wih = (const float*)d_in[7];
  const float* Whh = (const float*)d_in[8];
  const float* bih = (const float*)d_in[9];
  const float* bhh = (const float*)d_in[10];
  const float* Ws_W = (const float*)d_in[11];
  const float* Ws_b = (const float*)d_in[12];
  const float* Wo_W = (const float*)d_in[13];
  const float* Wo_b = (const float*)d_in[14];
  const float* Wc_W = (const float*)d_in[15];
  const float* Wc_b = (const float*)d_in[16];

  float* ws = (float*)d_ws;
  float* out = (float*)d_out;
  ushort* x_bf = (ushort*)(ws + XBF_OFF);
  float* h0 = ws + H0_OFF;
  ushort* h0_bf = (ushort*)(ws + H0BF_OFF);
  float* gi = ws + GI_OFF;
  float* gh = ws + GH_OFF;
  ushort* state_bf = (ushort*)(ws + STBF_OFF);
  ushort* Wc_bf = (ushort*)(ws + WCBF_OFF);
  float* score_c = ws + SC_OFF;
  float* red4 = ws + RED4_OFF;
  float* red = ws + RED_OFF;
  float* state = out + OUT_STATE;
  float* wout = out + OUT_W;

  kcvt<<<512, 256, 0, stream>>>(Wc_W, Wc_bf);  // 512*1024 / 4-per-thread / 256
  k0_build<<<64, 256, 0, stream>>>(input_idx, encoded, prev_state, weighted, order_p,
                                   embed_W, Ws_W, Ws_b, x_bf, h0, h0_bf);
  mfma_bt<KX><<<24, 256, 0, stream>>>(x_bf, Wih, bih, gi, G3);
  mfma_bt<H_DIM><<<24, 256, 0, stream>>>(h0_bf, Whh, bhh, gh, G3);
  k2_gru<<<64, 512, 0, stream>>>(gi, gh, h0, state, state_bf);
  mfma_bt<H_DIM><<<782, 256, 0, stream>>>(state_bf, Wo_W, Wo_b, out, V);
  k4_mfma<<<200, 256, 0, stream>>>(encoded, Wc_bf, Wc_b, state, score_c);
  k6_red<<<dim3(64, 4), 256, 0, stream>>>(out, score_c, encoded_idx, red4);
  k6b_combine<<<1, 64, 0, stream>>>(red4, red);
  k7_probs<<<3125, 256, 0, stream>>>(out, red);
  k8_copy<<<64, 256, 0, stream>>>(score_c, encoded_idx, input_idx, red, encoded, out, wout);
}